// Round 2
// baseline (2677.170 us; speedup 1.0000x reference)
//
#include <hip/hip_runtime.h>
#include <math.h>

// Problem constants
namespace {
constexpr int B = 2, C = 16, D = 16, H = 128, W = 128;
constexpr int HW   = H * W;        // 16384
constexpr int DHW  = D * HW;       // 262144
constexpr int CDHW = C * DHW;      // 4194304
constexpr float EPSBN = 1e-5f;

// workspace offsets (in floats); total 37,748,736 floats = 151 MB
constexpr long long OFF_X1  = 0;
constexpr long long OFF_X2  = 8388608;
constexpr long long OFF_Q   = 16777216;  // (B,D,2,H,W)
constexpr long long OFF_K   = 17825792;  // (B,D,2,H,W)
constexpr long long OFF_V   = 18874368;  // (B,D,16,H,W)
constexpr long long OFF_KT  = 27262976;  // (B,D,2,W,H)
constexpr long long OFF_VT  = 28311552;  // (B,D,16,W,H)
constexpr long long OFF_MST = 36700160;  // (B,D,2,W,H): m, 1/s
// gate buffers (reuse regions freed after attention 2):
constexpr long long OFF_G0  = OFF_X2;        // raw Wx conv (8.39M floats)
constexpr long long OFF_G1  = OFF_Q;         // raw ft conv (8.39M floats, spans Q/K/V region)
constexpr long long OFF_G2  = OFF_KT;        // raw rt conv (8.39M floats, spans KT/VT/MST region)
// raw X conv goes into d_out (same element indexing as final output)
}

// ---------------------------------------------------------------------------
// K1: conv_pre (1x3x3, pad 0,1,1) + BN + ReLU.   grid(64, D, B), block 256.
// ---------------------------------------------------------------------------
__global__ __launch_bounds__(256) void k_conv_pre(
    const float* __restrict__ x, const float* __restrict__ wp,
    const float* __restrict__ bg, const float* __restrict__ bb,
    const float* __restrict__ bm, const float* __restrict__ bv,
    float* __restrict__ out)
{
  __shared__ float xs[16][18][18];
  __shared__ float sc[16], bi[16];
  const int tid = threadIdx.x;
  const int tile = blockIdx.x;              // 0..63
  const int d = blockIdx.y, b = blockIdx.z;
  const int h0 = (tile >> 3) * 16, w0 = (tile & 7) * 16;

  if (tid < 16) {
    float s = bg[tid] * rsqrtf(bv[tid] + EPSBN);
    sc[tid] = s;
    bi[tid] = bb[tid] - bm[tid] * s;
  }
  const float* xb = x + (long long)b * CDHW + (long long)d * HW;
  for (int idx = tid; idx < 16 * 324; idx += 256) {
    int cin = idx / 324, rem = idx - cin * 324;
    int ph = rem / 18, pw = rem - ph * 18;
    int gh = h0 - 1 + ph, gw = w0 - 1 + pw;
    float v = 0.f;
    if (gh >= 0 && gh < H && gw >= 0 && gw < W)
      v = xb[(long long)cin * DHW + gh * W + gw];
    xs[cin][ph][pw] = v;
  }
  __syncthreads();

  const int ty = tid >> 4, tx = tid & 15;
  float acc[16];
  #pragma unroll
  for (int co = 0; co < 16; ++co) acc[co] = 0.f;

  for (int cin = 0; cin < 16; ++cin) {
    #pragma unroll
    for (int kh = 0; kh < 3; ++kh) {
      #pragma unroll
      for (int kw = 0; kw < 3; ++kw) {
        float xv = xs[cin][ty + kh][tx + kw];
        const int wi = cin * 9 + kh * 3 + kw;   // uniform -> s_load weights
        #pragma unroll
        for (int co = 0; co < 16; ++co)
          acc[co] = fmaf(xv, wp[co * 144 + wi], acc[co]);
      }
    }
  }
  float* ob = out + (long long)b * CDHW + (long long)d * HW + (h0 + ty) * W + (w0 + tx);
  #pragma unroll
  for (int co = 0; co < 16; ++co)
    ob[(long long)co * DHW] = fmaxf(fmaf(acc[co], sc[co], bi[co]), 0.f);
}

// ---------------------------------------------------------------------------
// K2: q,k,v projections + transposed copies.  grid(64, D, B), block 256.
// ---------------------------------------------------------------------------
__global__ __launch_bounds__(256) void k_qkv(
    const float* __restrict__ xin, const float* __restrict__ wq,
    const float* __restrict__ wk, const float* __restrict__ wv,
    float* __restrict__ Qp, float* __restrict__ Kp, float* __restrict__ Vp,
    float* __restrict__ KTp, float* __restrict__ VTp)
{
  const int tid = threadIdx.x;
  const int tile = blockIdx.x, d = blockIdx.y, b = blockIdx.z;
  const int h0 = (tile >> 3) * 16, w0 = (tile & 7) * 16;
  const int ty = tid >> 4, tx = tid & 15;
  const int h = h0 + ty, w = w0 + tx;

  const float* xb = xin + (long long)b * CDHW + (long long)d * HW + h * W + w;
  float xv[16];
  #pragma unroll
  for (int c = 0; c < 16; ++c) xv[c] = xb[(long long)c * DHW];

  float q0 = 0, q1 = 0, k0 = 0, k1 = 0, v[16];
  #pragma unroll
  for (int c = 0; c < 16; ++c) {
    q0 = fmaf(wq[c], xv[c], q0);
    q1 = fmaf(wq[16 + c], xv[c], q1);
    k0 = fmaf(wk[c], xv[c], k0);
    k1 = fmaf(wk[16 + c], xv[c], k1);
  }
  #pragma unroll
  for (int o = 0; o < 16; ++o) {
    float a = 0;
    #pragma unroll
    for (int c = 0; c < 16; ++c) a = fmaf(wv[o * 16 + c], xv[c], a);
    v[o] = a;
  }

  const int sl = b * 16 + d;
  const int hw = h * W + w;
  Qp[(long long)(sl * 2 + 0) * HW + hw] = q0;
  Qp[(long long)(sl * 2 + 1) * HW + hw] = q1;
  Kp[(long long)(sl * 2 + 0) * HW + hw] = k0;
  Kp[(long long)(sl * 2 + 1) * HW + hw] = k1;
  #pragma unroll
  for (int o = 0; o < 16; ++o) Vp[(long long)(sl * 16 + o) * HW + hw] = v[o];

  __shared__ float lsk[2][16][17];
  __shared__ float lsv[16][16][17];
  lsk[0][ty][tx] = k0; lsk[1][ty][tx] = k1;
  #pragma unroll
  for (int o = 0; o < 16; ++o) lsv[o][ty][tx] = v[o];
  __syncthreads();

  const int wh = (w0 + ty) * 128 + (h0 + tx);   // (w, h) coords transposed
  KTp[(long long)(sl * 2 + 0) * HW + wh] = lsk[0][tx][ty];
  KTp[(long long)(sl * 2 + 1) * HW + wh] = lsk[1][tx][ty];
  #pragma unroll
  for (int o = 0; o < 16; ++o) VTp[(long long)(sl * 16 + o) * HW + wh] = lsv[o][tx][ty];
}

// ---------------------------------------------------------------------------
// K3: softmax stats (eH with diag mask + eW) + oW term.
// block 128 = 4 h-rows x 32 lanes, each thread owns 4 w's. grid(32, D, B).
// writes out = xin + gamma*oW ; writes MST (m, 1/s) in W-major.
// ---------------------------------------------------------------------------
__global__ __launch_bounds__(128, 1) void k_att_row(
    const float* __restrict__ xin, float* __restrict__ out,
    const float* __restrict__ Qp, const float* __restrict__ Kp,
    const float* __restrict__ Vp, float* __restrict__ MSTp,
    const float* __restrict__ gp)
{
  __shared__ float krow[4][2][128];
  __shared__ __align__(16) float vrow[4][128][20];  // [hi][v][c], pad 16->20
  const int tid = threadIdx.x;
  const int h0 = blockIdx.x * 4, d = blockIdx.y, b = blockIdx.z;
  const int sl = b * 16 + d;
  const long long base2 = (long long)(sl * 2) * HW;
  const long long baseV = (long long)(sl * 16) * HW;
  const int hi = tid >> 5, wt = tid & 31;
  const int h = h0 + hi;

  // cooperative loads (lane index = fastest dim -> coalesced)
  for (int kk = 0; kk < 8; ++kk) {            // 4*2*128 / 128
    int o = kk & 1, r2 = kk >> 1;
    krow[r2][o][tid] = Kp[base2 + (long long)o * HW + (h0 + r2) * W + tid];
  }
  for (int kk = 0; kk < 64; ++kk) {           // 4*128*16 / 128
    int hi2 = kk & 3, c2 = kk >> 2;
    vrow[hi2][tid][c2] = Vp[baseV + (long long)c2 * HW + (h0 + hi2) * W + tid];
  }
  __syncthreads();

  const float* K0 = Kp + base2;
  const float* K1 = Kp + base2 + HW;
  int wr[4]; float q0[4], q1[4];
  #pragma unroll
  for (int r = 0; r < 4; ++r) {
    wr[r] = wt + 32 * r;
    q0[r] = Qp[base2 + h * W + wr[r]];
    q1[r] = Qp[base2 + HW + h * W + wr[r]];
  }

  // pass 1: max over eH (masked diag) and eW
  float m[4] = {-3e38f, -3e38f, -3e38f, -3e38f};
  for (int j = 0; j < 128; ++j) {
    #pragma unroll
    for (int r = 0; r < 4; ++r) {
      float e = fmaf(q0[r], K0[j * W + wr[r]], q1[r] * K1[j * W + wr[r]]);
      e = (j == h) ? -3e38f : e;
      m[r] = fmaxf(m[r], e);
    }
  }
  for (int v = 0; v < 128; ++v) {
    float kv0 = krow[hi][0][v], kv1 = krow[hi][1][v];
    #pragma unroll
    for (int r = 0; r < 4; ++r)
      m[r] = fmaxf(m[r], fmaf(q0[r], kv0, q1[r] * kv1));
  }

  // pass 2: sum of exp; fuse oW accumulation on the eW half
  float s[4] = {0.f, 0.f, 0.f, 0.f};
  float acc[4][16];
  #pragma unroll
  for (int r = 0; r < 4; ++r)
    #pragma unroll
    for (int c = 0; c < 16; ++c) acc[r][c] = 0.f;

  for (int j = 0; j < 128; ++j) {
    #pragma unroll
    for (int r = 0; r < 4; ++r) {
      float e = fmaf(q0[r], K0[j * W + wr[r]], q1[r] * K1[j * W + wr[r]]);
      float a = (j == h) ? 0.f : __expf(e - m[r]);
      s[r] += a;
    }
  }
  for (int v = 0; v < 128; ++v) {
    float kv0 = krow[hi][0][v], kv1 = krow[hi][1][v];
    const float4 V0 = *(const float4*)&vrow[hi][v][0];
    const float4 V1 = *(const float4*)&vrow[hi][v][4];
    const float4 V2 = *(const float4*)&vrow[hi][v][8];
    const float4 V3 = *(const float4*)&vrow[hi][v][12];
    #pragma unroll
    for (int r = 0; r < 4; ++r) {
      float e = fmaf(q0[r], kv0, q1[r] * kv1);
      float a = __expf(e - m[r]);
      s[r] += a;
      acc[r][0]  = fmaf(a, V0.x, acc[r][0]);  acc[r][1]  = fmaf(a, V0.y, acc[r][1]);
      acc[r][2]  = fmaf(a, V0.z, acc[r][2]);  acc[r][3]  = fmaf(a, V0.w, acc[r][3]);
      acc[r][4]  = fmaf(a, V1.x, acc[r][4]);  acc[r][5]  = fmaf(a, V1.y, acc[r][5]);
      acc[r][6]  = fmaf(a, V1.z, acc[r][6]);  acc[r][7]  = fmaf(a, V1.w, acc[r][7]);
      acc[r][8]  = fmaf(a, V2.x, acc[r][8]);  acc[r][9]  = fmaf(a, V2.y, acc[r][9]);
      acc[r][10] = fmaf(a, V2.z, acc[r][10]); acc[r][11] = fmaf(a, V2.w, acc[r][11]);
      acc[r][12] = fmaf(a, V3.x, acc[r][12]); acc[r][13] = fmaf(a, V3.y, acc[r][13]);
      acc[r][14] = fmaf(a, V3.z, acc[r][14]); acc[r][15] = fmaf(a, V3.w, acc[r][15]);
    }
  }

  const float gamma = gp[0];
  const long long ob = (long long)b * CDHW + (long long)d * HW + h * W;
  #pragma unroll
  for (int r = 0; r < 4; ++r) {
    float inv = 1.f / s[r];
    MSTp[base2 + wr[r] * 128 + h] = m[r];
    MSTp[base2 + HW + wr[r] * 128 + h] = inv;
    float gi = gamma * inv;
    #pragma unroll
    for (int c = 0; c < 16; ++c) {
      long long idx = ob + (long long)c * DHW + wr[r];
      out[idx] = xin[idx] + gi * acc[r][c];
    }
  }
}

// ---------------------------------------------------------------------------
// K4: oH term, accumulated into out.
// block 128 = 4 w-cols x 32 lanes, each thread owns 4 h's. grid(32, D, B).
// ---------------------------------------------------------------------------
__global__ __launch_bounds__(128, 1) void k_att_col(
    float* __restrict__ out, const float* __restrict__ Qp,
    const float* __restrict__ KTp, const float* __restrict__ VTp,
    const float* __restrict__ MSTp, const float* __restrict__ gp)
{
  __shared__ float kc[4][2][128];
  __shared__ __align__(16) float vc[4][128][20];   // [wi][j][c]
  __shared__ float mmr[4][128], iir[4][128];
  const int tid = threadIdx.x;
  const int w0 = blockIdx.x * 4, d = blockIdx.y, b = blockIdx.z;
  const int sl = b * 16 + d;
  const long long base2 = (long long)(sl * 2) * HW;
  const long long baseV = (long long)(sl * 16) * HW;
  const int wi = tid >> 5, hi = tid & 31;
  const int w = w0 + wi;

  for (int kk = 0; kk < 8; ++kk) {
    int o = kk & 1, r2 = kk >> 1;
    kc[r2][o][tid] = KTp[base2 + (long long)o * HW + (w0 + r2) * 128 + tid];
  }
  for (int kk = 0; kk < 64; ++kk) {
    int wi2 = kk & 3, c2 = kk >> 2;
    vc[wi2][tid][c2] = VTp[baseV + (long long)c2 * HW + (w0 + wi2) * 128 + tid];
  }
  for (int kk = 0; kk < 4; ++kk) {
    mmr[kk][tid] = MSTp[base2 + (w0 + kk) * 128 + tid];
    iir[kk][tid] = MSTp[base2 + HW + (w0 + kk) * 128 + tid];
  }
  __syncthreads();

  int hr[4]; float q0[4], q1[4], m[4], is[4];
  #pragma unroll
  for (int r = 0; r < 4; ++r) {
    hr[r] = hi + 32 * r;
    q0[r] = Qp[base2 + hr[r] * W + w];
    q1[r] = Qp[base2 + HW + hr[r] * W + w];
    m[r]  = mmr[wi][hr[r]];
    is[r] = iir[wi][hr[r]];
  }
  float acc[4][16];
  #pragma unroll
  for (int r = 0; r < 4; ++r)
    #pragma unroll
    for (int c = 0; c < 16; ++c) acc[r][c] = 0.f;

  for (int j = 0; j < 128; ++j) {
    float k0 = kc[wi][0][j], k1 = kc[wi][1][j];
    const float4 V0 = *(const float4*)&vc[wi][j][0];
    const float4 V1 = *(const float4*)&vc[wi][j][4];
    const float4 V2 = *(const float4*)&vc[wi][j][8];
    const float4 V3 = *(const float4*)&vc[wi][j][12];
    #pragma unroll
    for (int r = 0; r < 4; ++r) {
      float e = fmaf(q0[r], k0, q1[r] * k1);
      float a = (j == hr[r]) ? 0.f : __expf(e - m[r]);
      acc[r][0]  = fmaf(a, V0.x, acc[r][0]);  acc[r][1]  = fmaf(a, V0.y, acc[r][1]);
      acc[r][2]  = fmaf(a, V0.z, acc[r][2]);  acc[r][3]  = fmaf(a, V0.w, acc[r][3]);
      acc[r][4]  = fmaf(a, V1.x, acc[r][4]);  acc[r][5]  = fmaf(a, V1.y, acc[r][5]);
      acc[r][6]  = fmaf(a, V1.z, acc[r][6]);  acc[r][7]  = fmaf(a, V1.w, acc[r][7]);
      acc[r][8]  = fmaf(a, V2.x, acc[r][8]);  acc[r][9]  = fmaf(a, V2.y, acc[r][9]);
      acc[r][10] = fmaf(a, V2.z, acc[r][10]); acc[r][11] = fmaf(a, V2.w, acc[r][11]);
      acc[r][12] = fmaf(a, V3.x, acc[r][12]); acc[r][13] = fmaf(a, V3.y, acc[r][13]);
      acc[r][14] = fmaf(a, V3.z, acc[r][14]); acc[r][15] = fmaf(a, V3.w, acc[r][15]);
    }
  }

  const float gamma = gp[0];
  const long long ob = (long long)b * CDHW + (long long)d * HW;
  #pragma unroll
  for (int r = 0; r < 4; ++r) {
    float gi = gamma * is[r];
    #pragma unroll
    for (int c = 0; c < 16; ++c)
      out[ob + (long long)c * DHW + hr[r] * W + w] += gi * acc[r][c];
  }
}

// ---------------------------------------------------------------------------
// K5a: conv_gate (3x3x3, pad 1, 16->64ch), RAW outputs (BN/act deferred).
// grid(64, D, B), block 1024 = 4 output-groups x 256 pixels.
// LDS stages 3 d-slices x 16 cin x 18x18 halo once per block (62 KB).
// Each thread: 1 pixel, 16 output channels of one gate group.
// g0..g2 -> workspace, g3 (X gate) -> d_out (same indexing as final output;
// k_scan reads it before overwriting).
// ---------------------------------------------------------------------------
__global__ __launch_bounds__(1024) void k_gates(
    const float* __restrict__ x, const float* __restrict__ wg,
    float* __restrict__ g0, float* __restrict__ g1,
    float* __restrict__ g2, float* __restrict__ g3)
{
  __shared__ float xs[3][16][18][18];
  const int tid = threadIdx.x;
  const int tile = blockIdx.x;
  const int d = blockIdx.y, b = blockIdx.z;
  const int h0 = (tile >> 3) * 16, w0 = (tile & 7) * 16;

  const float* xb = x + (long long)b * CDHW;
  for (int idx = tid; idx < 3 * 16 * 324; idx += 1024) {
    int kd = idx / 5184, rem = idx - kd * 5184;
    int cin = rem / 324, r2 = rem - cin * 324;
    int ph = r2 / 18, pw = r2 - ph * 18;
    int dd = d - 1 + kd, gh = h0 - 1 + ph, gw = w0 - 1 + pw;
    float v = 0.f;
    if (dd >= 0 && dd < D && gh >= 0 && gh < H && gw >= 0 && gw < W)
      v = xb[(long long)cin * DHW + dd * HW + gh * W + gw];
    xs[kd][cin][ph][pw] = v;
  }
  __syncthreads();

  const int p = tid & 255;          // pixel within tile
  const int og = tid >> 8;          // gate group 0..3 (wave-uniform)
  const int ty = p >> 4, tx = p & 15;

  float acc[16];
  #pragma unroll
  for (int cc = 0; cc < 16; ++cc) acc[cc] = 0.f;

  for (int cin = 0; cin < 16; ++cin) {
    float xr[27];
    #pragma unroll
    for (int kd = 0; kd < 3; ++kd)
      #pragma unroll
      for (int kh = 0; kh < 3; ++kh)
        #pragma unroll
        for (int kw = 0; kw < 3; ++kw)
          xr[kd * 9 + kh * 3 + kw] = xs[kd][cin][ty + kh][tx + kw];

    const float* wb = wg + (long long)(og * 16) * 432 + cin * 27;
    #pragma unroll
    for (int cc = 0; cc < 16; ++cc) {
      const float* wc = wb + cc * 432;
      #pragma unroll
      for (int t = 0; t < 27; ++t)
        acc[cc] = fmaf(xr[t], wc[t], acc[cc]);
    }
  }

  float* gbuf = (og == 0) ? g0 : (og == 1) ? g1 : (og == 2) ? g2 : g3;
  const int h = h0 + ty, w = w0 + tx;
  const long long base = (long long)b * CDHW + (long long)d * HW + h * W + w;
  #pragma unroll
  for (int cc = 0; cc < 16; ++cc)
    gbuf[base + (long long)cc * DHW] = acc[cc];
}

// ---------------------------------------------------------------------------
// K5b: BN + activations + SRU scan over D. One thread per (b,c,h,w).
// grid 2048 x 256. Reads raw gates (g3 lives in d_out; read-before-write
// at the same index within each thread's sequential d loop).
// ---------------------------------------------------------------------------
__global__ __launch_bounds__(256) void k_scan(
    const float* __restrict__ g0, const float* __restrict__ g1,
    const float* __restrict__ g2, const float* __restrict__ g3,
    const float* __restrict__ bg, const float* __restrict__ bb,
    const float* __restrict__ bm, const float* __restrict__ bv,
    float* __restrict__ out)
{
  const int g = blockIdx.x * 256 + threadIdx.x;   // 0 .. 524287
  const int hw = g & 16383;
  const int cc = (g >> 14) & 15;
  const int b  = g >> 18;

  float sc[4], bi[4];
  #pragma unroll
  for (int gg = 0; gg < 4; ++gg) {
    int ch = gg * 16 + cc;
    float s = bg[ch] * rsqrtf(bv[ch] + EPSBN);
    sc[gg] = s;
    bi[gg] = bb[ch] - bm[ch] * s;
  }

  const long long base = (long long)b * CDHW + (long long)cc * DHW + hw;
  float Ct = 0.f;
  for (int d = 0; d < D; ++d) {
    const long long idx = base + (long long)d * HW;
    float wx = tanhf(fmaf(g0[idx], sc[0], bi[0]));
    float ft = 1.f / (1.f + __expf(-fmaf(g1[idx], sc[1], bi[1])));
    float rt = 1.f / (1.f + __expf(-fmaf(g2[idx], sc[2], bi[2])));
    float xg = tanhf(fmaf(g3[idx], sc[3], bi[3]));
    Ct = (d == 0) ? (1.f - ft) : fmaf(ft, Ct, (1.f - ft) * wx);
    out[idx] = fmaf(rt, Ct, (1.f - rt) * xg);
  }
}

// ---------------------------------------------------------------------------
extern "C" void kernel_launch(void* const* d_in, const int* in_sizes, int n_in,
                              void* d_out, int out_size, void* d_ws, size_t ws_size,
                              hipStream_t stream) {
  const float* x      = (const float*)d_in[0];
  const float* w_pre  = (const float*)d_in[1];
  const float* bnpg   = (const float*)d_in[2];
  const float* bnpb   = (const float*)d_in[3];
  const float* bnpm   = (const float*)d_in[4];
  const float* bnpv   = (const float*)d_in[5];
  const float* wq     = (const float*)d_in[6];
  const float* wk     = (const float*)d_in[7];
  const float* wv     = (const float*)d_in[8];
  const float* gamma  = (const float*)d_in[9];
  const float* w_gate = (const float*)d_in[10];
  const float* bng    = (const float*)d_in[11];
  const float* bnb    = (const float*)d_in[12];
  const float* bnm    = (const float*)d_in[13];
  const float* bnv    = (const float*)d_in[14];

  float* ws  = (float*)d_ws;
  float* X1  = ws + OFF_X1;
  float* X2  = ws + OFF_X2;
  float* Q   = ws + OFF_Q;
  float* K   = ws + OFF_K;
  float* V   = ws + OFF_V;
  float* KT  = ws + OFF_KT;
  float* VT  = ws + OFF_VT;
  float* MST = ws + OFF_MST;
  float* G0  = ws + OFF_G0;
  float* G1  = ws + OFF_G1;
  float* G2  = ws + OFF_G2;
  float* out = (float*)d_out;

  // stage 1: conv_pre + BN + ReLU -> X1
  k_conv_pre<<<dim3(64, D, B), dim3(256), 0, stream>>>(x, w_pre, bnpg, bnpb, bnpm, bnpv, X1);

  // attention application 1: X1 -> X2
  k_qkv    <<<dim3(64, D, B), dim3(256), 0, stream>>>(X1, wq, wk, wv, Q, K, V, KT, VT);
  k_att_row<<<dim3(32, D, B), dim3(128), 0, stream>>>(X1, X2, Q, K, V, MST, gamma);
  k_att_col<<<dim3(32, D, B), dim3(128), 0, stream>>>(X2, Q, KT, VT, MST, gamma);

  // attention application 2: X2 -> X1
  k_qkv    <<<dim3(64, D, B), dim3(256), 0, stream>>>(X2, wq, wk, wv, Q, K, V, KT, VT);
  k_att_row<<<dim3(32, D, B), dim3(128), 0, stream>>>(X2, X1, Q, K, V, MST, gamma);
  k_att_col<<<dim3(32, D, B), dim3(128), 0, stream>>>(X1, Q, KT, VT, MST, gamma);

  // stage 3: conv_gate raw outputs (G0..G2 in ws, X gate into d_out)
  k_gates<<<dim3(64, D, B), dim3(1024), 0, stream>>>(X1, w_gate, G0, G1, G2, out);

  // stage 4: BN + activations + SRU scan
  k_scan<<<dim3(2048), dim3(256), 0, stream>>>(G0, G1, G2, out, bng, bnb, bnm, bnv, out);
}

// Round 3
// 1792.153 us; speedup vs baseline: 1.4938x; 1.4938x over previous
//
#include <hip/hip_runtime.h>
#include <math.h>

// Problem constants
namespace {
constexpr int B = 2, C = 16, D = 16, H = 128, W = 128;
constexpr int HW   = H * W;        // 16384
constexpr int DHW  = D * HW;       // 262144
constexpr int CDHW = C * DHW;      // 4194304
constexpr float EPSBN = 1e-5f;

// workspace offsets (in floats); total 37,748,736 floats = 151 MB
constexpr long long OFF_X1  = 0;
constexpr long long OFF_X2  = 8388608;
constexpr long long OFF_Q   = 16777216;  // (B,D,2,H,W)
constexpr long long OFF_K   = 17825792;  // (B,D,2,H,W)
constexpr long long OFF_V   = 18874368;  // (B,D,16,H,W)
constexpr long long OFF_KT  = 27262976;  // (B,D,2,W,H)
constexpr long long OFF_VT  = 28311552;  // (B,D,16,W,H)
constexpr long long OFF_MST = 36700160;  // (B,D,2,W,H): m, 1/s
// gate buffers (reuse regions freed after attention 2):
constexpr long long OFF_G0  = OFF_X2;    // raw Wx conv
constexpr long long OFF_G1  = OFF_Q;     // raw ft conv
constexpr long long OFF_G2  = OFF_KT;    // raw rt conv
// transposed gate weights WT[cin][tap][co] (27648 floats) -> MST region
constexpr long long OFF_WT  = OFF_MST;
// raw X conv goes into d_out
}

// ---------------------------------------------------------------------------
// K1: conv_pre (1x3x3, pad 0,1,1) + BN + ReLU.   grid(64, D, B), block 256.
// ---------------------------------------------------------------------------
__global__ __launch_bounds__(256) void k_conv_pre(
    const float* __restrict__ x, const float* __restrict__ wp,
    const float* __restrict__ bg, const float* __restrict__ bb,
    const float* __restrict__ bm, const float* __restrict__ bv,
    float* __restrict__ out)
{
  __shared__ float xs[16][18][18];
  __shared__ float sc[16], bi[16];
  const int tid = threadIdx.x;
  const int tile = blockIdx.x;              // 0..63
  const int d = blockIdx.y, b = blockIdx.z;
  const int h0 = (tile >> 3) * 16, w0 = (tile & 7) * 16;

  if (tid < 16) {
    float s = bg[tid] * rsqrtf(bv[tid] + EPSBN);
    sc[tid] = s;
    bi[tid] = bb[tid] - bm[tid] * s;
  }
  const float* xb = x + (long long)b * CDHW + (long long)d * HW;
  for (int idx = tid; idx < 16 * 324; idx += 256) {
    int cin = idx / 324, rem = idx - cin * 324;
    int ph = rem / 18, pw = rem - ph * 18;
    int gh = h0 - 1 + ph, gw = w0 - 1 + pw;
    float v = 0.f;
    if (gh >= 0 && gh < H && gw >= 0 && gw < W)
      v = xb[(long long)cin * DHW + gh * W + gw];
    xs[cin][ph][pw] = v;
  }
  __syncthreads();

  const int ty = tid >> 4, tx = tid & 15;
  float acc[16];
  #pragma unroll
  for (int co = 0; co < 16; ++co) acc[co] = 0.f;

  for (int cin = 0; cin < 16; ++cin) {
    #pragma unroll
    for (int kh = 0; kh < 3; ++kh) {
      #pragma unroll
      for (int kw = 0; kw < 3; ++kw) {
        float xv = xs[cin][ty + kh][tx + kw];
        const int wi = cin * 9 + kh * 3 + kw;
        #pragma unroll
        for (int co = 0; co < 16; ++co)
          acc[co] = fmaf(xv, wp[co * 144 + wi], acc[co]);
      }
    }
  }
  float* ob = out + (long long)b * CDHW + (long long)d * HW + (h0 + ty) * W + (w0 + tx);
  #pragma unroll
  for (int co = 0; co < 16; ++co)
    ob[(long long)co * DHW] = fmaxf(fmaf(acc[co], sc[co], bi[co]), 0.f);
}

// ---------------------------------------------------------------------------
// K2: q,k,v projections + transposed copies.  grid(64, D, B), block 256.
// ---------------------------------------------------------------------------
__global__ __launch_bounds__(256) void k_qkv(
    const float* __restrict__ xin, const float* __restrict__ wq,
    const float* __restrict__ wk, const float* __restrict__ wv,
    float* __restrict__ Qp, float* __restrict__ Kp, float* __restrict__ Vp,
    float* __restrict__ KTp, float* __restrict__ VTp)
{
  const int tid = threadIdx.x;
  const int tile = blockIdx.x, d = blockIdx.y, b = blockIdx.z;
  const int h0 = (tile >> 3) * 16, w0 = (tile & 7) * 16;
  const int ty = tid >> 4, tx = tid & 15;
  const int h = h0 + ty, w = w0 + tx;

  const float* xb = xin + (long long)b * CDHW + (long long)d * HW + h * W + w;
  float xv[16];
  #pragma unroll
  for (int c = 0; c < 16; ++c) xv[c] = xb[(long long)c * DHW];

  float q0 = 0, q1 = 0, k0 = 0, k1 = 0, v[16];
  #pragma unroll
  for (int c = 0; c < 16; ++c) {
    q0 = fmaf(wq[c], xv[c], q0);
    q1 = fmaf(wq[16 + c], xv[c], q1);
    k0 = fmaf(wk[c], xv[c], k0);
    k1 = fmaf(wk[16 + c], xv[c], k1);
  }
  #pragma unroll
  for (int o = 0; o < 16; ++o) {
    float a = 0;
    #pragma unroll
    for (int c = 0; c < 16; ++c) a = fmaf(wv[o * 16 + c], xv[c], a);
    v[o] = a;
  }

  const int sl = b * 16 + d;
  const int hw = h * W + w;
  Qp[(long long)(sl * 2 + 0) * HW + hw] = q0;
  Qp[(long long)(sl * 2 + 1) * HW + hw] = q1;
  Kp[(long long)(sl * 2 + 0) * HW + hw] = k0;
  Kp[(long long)(sl * 2 + 1) * HW + hw] = k1;
  #pragma unroll
  for (int o = 0; o < 16; ++o) Vp[(long long)(sl * 16 + o) * HW + hw] = v[o];

  __shared__ float lsk[2][16][17];
  __shared__ float lsv[16][16][17];
  lsk[0][ty][tx] = k0; lsk[1][ty][tx] = k1;
  #pragma unroll
  for (int o = 0; o < 16; ++o) lsv[o][ty][tx] = v[o];
  __syncthreads();

  const int wh = (w0 + ty) * 128 + (h0 + tx);
  KTp[(long long)(sl * 2 + 0) * HW + wh] = lsk[0][tx][ty];
  KTp[(long long)(sl * 2 + 1) * HW + wh] = lsk[1][tx][ty];
  #pragma unroll
  for (int o = 0; o < 16; ++o) VTp[(long long)(sl * 16 + o) * HW + wh] = lsv[o][tx][ty];
}

// ---------------------------------------------------------------------------
// K3: softmax stats (eH with diag mask + eW) + oW term.
// ---------------------------------------------------------------------------
__global__ __launch_bounds__(128, 1) void k_att_row(
    const float* __restrict__ xin, float* __restrict__ out,
    const float* __restrict__ Qp, const float* __restrict__ Kp,
    const float* __restrict__ Vp, float* __restrict__ MSTp,
    const float* __restrict__ gp)
{
  __shared__ float krow[4][2][128];
  __shared__ __align__(16) float vrow[4][128][20];
  const int tid = threadIdx.x;
  const int h0 = blockIdx.x * 4, d = blockIdx.y, b = blockIdx.z;
  const int sl = b * 16 + d;
  const long long base2 = (long long)(sl * 2) * HW;
  const long long baseV = (long long)(sl * 16) * HW;
  const int hi = tid >> 5, wt = tid & 31;
  const int h = h0 + hi;

  for (int kk = 0; kk < 8; ++kk) {
    int o = kk & 1, r2 = kk >> 1;
    krow[r2][o][tid] = Kp[base2 + (long long)o * HW + (h0 + r2) * W + tid];
  }
  for (int kk = 0; kk < 64; ++kk) {
    int hi2 = kk & 3, c2 = kk >> 2;
    vrow[hi2][tid][c2] = Vp[baseV + (long long)c2 * HW + (h0 + hi2) * W + tid];
  }
  __syncthreads();

  const float* K0 = Kp + base2;
  const float* K1 = Kp + base2 + HW;
  int wr[4]; float q0[4], q1[4];
  #pragma unroll
  for (int r = 0; r < 4; ++r) {
    wr[r] = wt + 32 * r;
    q0[r] = Qp[base2 + h * W + wr[r]];
    q1[r] = Qp[base2 + HW + h * W + wr[r]];
  }

  float m[4] = {-3e38f, -3e38f, -3e38f, -3e38f};
  for (int j = 0; j < 128; ++j) {
    #pragma unroll
    for (int r = 0; r < 4; ++r) {
      float e = fmaf(q0[r], K0[j * W + wr[r]], q1[r] * K1[j * W + wr[r]]);
      e = (j == h) ? -3e38f : e;
      m[r] = fmaxf(m[r], e);
    }
  }
  for (int v = 0; v < 128; ++v) {
    float kv0 = krow[hi][0][v], kv1 = krow[hi][1][v];
    #pragma unroll
    for (int r = 0; r < 4; ++r)
      m[r] = fmaxf(m[r], fmaf(q0[r], kv0, q1[r] * kv1));
  }

  float s[4] = {0.f, 0.f, 0.f, 0.f};
  float acc[4][16];
  #pragma unroll
  for (int r = 0; r < 4; ++r)
    #pragma unroll
    for (int c = 0; c < 16; ++c) acc[r][c] = 0.f;

  for (int j = 0; j < 128; ++j) {
    #pragma unroll
    for (int r = 0; r < 4; ++r) {
      float e = fmaf(q0[r], K0[j * W + wr[r]], q1[r] * K1[j * W + wr[r]]);
      float a = (j == h) ? 0.f : __expf(e - m[r]);
      s[r] += a;
    }
  }
  for (int v = 0; v < 128; ++v) {
    float kv0 = krow[hi][0][v], kv1 = krow[hi][1][v];
    const float4 V0 = *(const float4*)&vrow[hi][v][0];
    const float4 V1 = *(const float4*)&vrow[hi][v][4];
    const float4 V2 = *(const float4*)&vrow[hi][v][8];
    const float4 V3 = *(const float4*)&vrow[hi][v][12];
    #pragma unroll
    for (int r = 0; r < 4; ++r) {
      float e = fmaf(q0[r], kv0, q1[r] * kv1);
      float a = __expf(e - m[r]);
      s[r] += a;
      acc[r][0]  = fmaf(a, V0.x, acc[r][0]);  acc[r][1]  = fmaf(a, V0.y, acc[r][1]);
      acc[r][2]  = fmaf(a, V0.z, acc[r][2]);  acc[r][3]  = fmaf(a, V0.w, acc[r][3]);
      acc[r][4]  = fmaf(a, V1.x, acc[r][4]);  acc[r][5]  = fmaf(a, V1.y, acc[r][5]);
      acc[r][6]  = fmaf(a, V1.z, acc[r][6]);  acc[r][7]  = fmaf(a, V1.w, acc[r][7]);
      acc[r][8]  = fmaf(a, V2.x, acc[r][8]);  acc[r][9]  = fmaf(a, V2.y, acc[r][9]);
      acc[r][10] = fmaf(a, V2.z, acc[r][10]); acc[r][11] = fmaf(a, V2.w, acc[r][11]);
      acc[r][12] = fmaf(a, V3.x, acc[r][12]); acc[r][13] = fmaf(a, V3.y, acc[r][13]);
      acc[r][14] = fmaf(a, V3.z, acc[r][14]); acc[r][15] = fmaf(a, V3.w, acc[r][15]);
    }
  }

  const float gamma = gp[0];
  const long long ob = (long long)b * CDHW + (long long)d * HW + h * W;
  #pragma unroll
  for (int r = 0; r < 4; ++r) {
    float inv = 1.f / s[r];
    MSTp[base2 + wr[r] * 128 + h] = m[r];
    MSTp[base2 + HW + wr[r] * 128 + h] = inv;
    float gi = gamma * inv;
    #pragma unroll
    for (int c = 0; c < 16; ++c) {
      long long idx = ob + (long long)c * DHW + wr[r];
      out[idx] = xin[idx] + gi * acc[r][c];
    }
  }
}

// ---------------------------------------------------------------------------
// K4: oH term, accumulated into out.
// ---------------------------------------------------------------------------
__global__ __launch_bounds__(128, 1) void k_att_col(
    float* __restrict__ out, const float* __restrict__ Qp,
    const float* __restrict__ KTp, const float* __restrict__ VTp,
    const float* __restrict__ MSTp, const float* __restrict__ gp)
{
  __shared__ float kc[4][2][128];
  __shared__ __align__(16) float vc[4][128][20];
  __shared__ float mmr[4][128], iir[4][128];
  const int tid = threadIdx.x;
  const int w0 = blockIdx.x * 4, d = blockIdx.y, b = blockIdx.z;
  const int sl = b * 16 + d;
  const long long base2 = (long long)(sl * 2) * HW;
  const long long baseV = (long long)(sl * 16) * HW;
  const int wi = tid >> 5, hi = tid & 31;
  const int w = w0 + wi;

  for (int kk = 0; kk < 8; ++kk) {
    int o = kk & 1, r2 = kk >> 1;
    kc[r2][o][tid] = KTp[base2 + (long long)o * HW + (w0 + r2) * 128 + tid];
  }
  for (int kk = 0; kk < 64; ++kk) {
    int wi2 = kk & 3, c2 = kk >> 2;
    vc[wi2][tid][c2] = VTp[baseV + (long long)c2 * HW + (w0 + wi2) * 128 + tid];
  }
  for (int kk = 0; kk < 4; ++kk) {
    mmr[kk][tid] = MSTp[base2 + (w0 + kk) * 128 + tid];
    iir[kk][tid] = MSTp[base2 + HW + (w0 + kk) * 128 + tid];
  }
  __syncthreads();

  int hr[4]; float q0[4], q1[4], m[4], is[4];
  #pragma unroll
  for (int r = 0; r < 4; ++r) {
    hr[r] = hi + 32 * r;
    q0[r] = Qp[base2 + hr[r] * W + w];
    q1[r] = Qp[base2 + HW + hr[r] * W + w];
    m[r]  = mmr[wi][hr[r]];
    is[r] = iir[wi][hr[r]];
  }
  float acc[4][16];
  #pragma unroll
  for (int r = 0; r < 4; ++r)
    #pragma unroll
    for (int c = 0; c < 16; ++c) acc[r][c] = 0.f;

  for (int j = 0; j < 128; ++j) {
    float k0 = kc[wi][0][j], k1 = kc[wi][1][j];
    const float4 V0 = *(const float4*)&vc[wi][j][0];
    const float4 V1 = *(const float4*)&vc[wi][j][4];
    const float4 V2 = *(const float4*)&vc[wi][j][8];
    const float4 V3 = *(const float4*)&vc[wi][j][12];
    #pragma unroll
    for (int r = 0; r < 4; ++r) {
      float e = fmaf(q0[r], k0, q1[r] * k1);
      float a = (j == hr[r]) ? 0.f : __expf(e - m[r]);
      acc[r][0]  = fmaf(a, V0.x, acc[r][0]);  acc[r][1]  = fmaf(a, V0.y, acc[r][1]);
      acc[r][2]  = fmaf(a, V0.z, acc[r][2]);  acc[r][3]  = fmaf(a, V0.w, acc[r][3]);
      acc[r][4]  = fmaf(a, V1.x, acc[r][4]);  acc[r][5]  = fmaf(a, V1.y, acc[r][5]);
      acc[r][6]  = fmaf(a, V1.z, acc[r][6]);  acc[r][7]  = fmaf(a, V1.w, acc[r][7]);
      acc[r][8]  = fmaf(a, V2.x, acc[r][8]);  acc[r][9]  = fmaf(a, V2.y, acc[r][9]);
      acc[r][10] = fmaf(a, V2.z, acc[r][10]); acc[r][11] = fmaf(a, V2.w, acc[r][11]);
      acc[r][12] = fmaf(a, V3.x, acc[r][12]); acc[r][13] = fmaf(a, V3.y, acc[r][13]);
      acc[r][14] = fmaf(a, V3.z, acc[r][14]); acc[r][15] = fmaf(a, V3.w, acc[r][15]);
    }
  }

  const float gamma = gp[0];
  const long long ob = (long long)b * CDHW + (long long)d * HW;
  #pragma unroll
  for (int r = 0; r < 4; ++r) {
    float gi = gamma * is[r];
    #pragma unroll
    for (int c = 0; c < 16; ++c)
      out[ob + (long long)c * DHW + hr[r] * W + w] += gi * acc[r][c];
  }
}

// ---------------------------------------------------------------------------
// K_wt: transpose gate weights OIDHW[co][cin][tap] -> WT[cin][tap][co].
// 27648 elements, trivial.
// ---------------------------------------------------------------------------
__global__ __launch_bounds__(256) void k_wt(
    const float* __restrict__ wg, float* __restrict__ WT)
{
  const int idx = blockIdx.x * 256 + threadIdx.x;   // < 27648
  if (idx >= 64 * 432) return;
  const int co = idx & 63;
  const int t2 = idx >> 6;          // cin*27 + tap
  const int cin = t2 / 27, tap = t2 - cin * 27;
  WT[cin * 1728 + tap * 64 + co] = wg[co * 432 + cin * 27 + tap];
}

// ---------------------------------------------------------------------------
// K5a v3: conv_gate (3x3x3, pad 1, 16->64ch), RAW outputs.
// grid(32 rowgroups, D, B), block 256 = 4 og-waves x 64 pixel-groups.
// Block computes 64co x 4rows x 128cols. Thread: 16co x 8 consecutive cols.
// Per-cin double-buffered LDS: x slab [3dd][6rows][132cols] + WT tap-major.
// FMA:LDS-instr ratio ~25:1 -> VALU-bound.
// ---------------------------------------------------------------------------
__global__ __launch_bounds__(256, 2) void k_gates(
    const float* __restrict__ x, const float* __restrict__ WT,
    float* __restrict__ g0, float* __restrict__ g1,
    float* __restrict__ g2, float* __restrict__ g3)
{
  __shared__ float xs[2][3][6][132];
  __shared__ float wl[2][27][64];
  const int tid = threadIdx.x;
  const int rg = blockIdx.x;                 // 0..31 (4-row group)
  const int d = blockIdx.y, b = blockIdx.z;
  const int h0 = rg * 4;

  const int og = tid >> 6;                   // wave-uniform gate group
  const int t  = tid & 63;
  const int pr = t >> 4;                     // row 0..3
  const int c0 = (t & 15) * 8;               // col start (8 cols/thread)

  const float* xb = x + (long long)b * CDHW;

  // ---- staging lambdas (inline) ----
  auto stage = [&](int buf, int cin) {
    // x slab: 3*6*130 = 2340 elements
    for (int idx = tid; idx < 2340; idx += 256) {
      int kd = idx / 780, rem = idx - kd * 780;
      int r = rem / 130, tt = rem - r * 130;
      int dd = d - 1 + kd, gh = h0 - 1 + r, gw = tt - 1;
      float v = 0.f;
      if (dd >= 0 && dd < D && gh >= 0 && gh < H && gw >= 0 && gw < W)
        v = xb[(long long)cin * DHW + dd * HW + gh * W + gw];
      xs[buf][kd][r][tt] = v;
    }
    // weights: 27*64 = 1728 elements, consecutive in WT
    const float* wsrc = WT + cin * 1728;
    for (int idx = tid; idx < 1728; idx += 256)
      wl[buf][idx >> 6][idx & 63] = wsrc[idx];
  };

  float acc[16][8];
  #pragma unroll
  for (int cc = 0; cc < 16; ++cc)
    #pragma unroll
    for (int j = 0; j < 8; ++j) acc[cc][j] = 0.f;

  stage(0, 0);
  __syncthreads();

  for (int cin = 0; cin < 16; ++cin) {
    const int buf = cin & 1;
    if (cin + 1 < 16) stage(buf ^ 1, cin + 1);

    #pragma unroll
    for (int kd = 0; kd < 3; ++kd) {
      #pragma unroll
      for (int kh = 0; kh < 3; ++kh) {
        float xr[12];
        *(float4*)&xr[0] = *(const float4*)&xs[buf][kd][pr + kh][c0];
        *(float4*)&xr[4] = *(const float4*)&xs[buf][kd][pr + kh][c0 + 4];
        *(float4*)&xr[8] = *(const float4*)&xs[buf][kd][pr + kh][c0 + 8];
        #pragma unroll
        for (int kw = 0; kw < 3; ++kw) {
          const int tap = kd * 9 + kh * 3 + kw;
          const float4 w0 = *(const float4*)&wl[buf][tap][og * 16 + 0];
          const float4 w1 = *(const float4*)&wl[buf][tap][og * 16 + 4];
          const float4 w2 = *(const float4*)&wl[buf][tap][og * 16 + 8];
          const float4 w3 = *(const float4*)&wl[buf][tap][og * 16 + 12];
          #pragma unroll
          for (int j = 0; j < 8; ++j) {
            const float xv = xr[kw + j];
            acc[0][j]  = fmaf(xv, w0.x, acc[0][j]);
            acc[1][j]  = fmaf(xv, w0.y, acc[1][j]);
            acc[2][j]  = fmaf(xv, w0.z, acc[2][j]);
            acc[3][j]  = fmaf(xv, w0.w, acc[3][j]);
            acc[4][j]  = fmaf(xv, w1.x, acc[4][j]);
            acc[5][j]  = fmaf(xv, w1.y, acc[5][j]);
            acc[6][j]  = fmaf(xv, w1.z, acc[6][j]);
            acc[7][j]  = fmaf(xv, w1.w, acc[7][j]);
            acc[8][j]  = fmaf(xv, w2.x, acc[8][j]);
            acc[9][j]  = fmaf(xv, w2.y, acc[9][j]);
            acc[10][j] = fmaf(xv, w2.z, acc[10][j]);
            acc[11][j] = fmaf(xv, w2.w, acc[11][j]);
            acc[12][j] = fmaf(xv, w3.x, acc[12][j]);
            acc[13][j] = fmaf(xv, w3.y, acc[13][j]);
            acc[14][j] = fmaf(xv, w3.z, acc[14][j]);
            acc[15][j] = fmaf(xv, w3.w, acc[15][j]);
          }
        }
      }
    }
    __syncthreads();
  }

  float* gbuf = (og == 0) ? g0 : (og == 1) ? g1 : (og == 2) ? g2 : g3;
  const long long base = (long long)b * CDHW + (long long)d * HW + (h0 + pr) * W + c0;
  #pragma unroll
  for (int cc = 0; cc < 16; ++cc) {
    float4 o0 = make_float4(acc[cc][0], acc[cc][1], acc[cc][2], acc[cc][3]);
    float4 o1 = make_float4(acc[cc][4], acc[cc][5], acc[cc][6], acc[cc][7]);
    *(float4*)&gbuf[base + (long long)cc * DHW]     = o0;
    *(float4*)&gbuf[base + (long long)cc * DHW + 4] = o1;
  }
}

// ---------------------------------------------------------------------------
// K5b: BN + activations + SRU scan over D. One thread per (b,c,h,w).
// ---------------------------------------------------------------------------
__global__ __launch_bounds__(256) void k_scan(
    const float* __restrict__ g0, const float* __restrict__ g1,
    const float* __restrict__ g2, const float* __restrict__ g3,
    const float* __restrict__ bg, const float* __restrict__ bb,
    const float* __restrict__ bm, const float* __restrict__ bv,
    float* __restrict__ out)
{
  const int g = blockIdx.x * 256 + threadIdx.x;   // 0 .. 524287
  const int hw = g & 16383;
  const int cc = (g >> 14) & 15;
  const int b  = g >> 18;

  float sc[4], bi[4];
  #pragma unroll
  for (int gg = 0; gg < 4; ++gg) {
    int ch = gg * 16 + cc;
    float s = bg[ch] * rsqrtf(bv[ch] + EPSBN);
    sc[gg] = s;
    bi[gg] = bb[ch] - bm[ch] * s;
  }

  const long long base = (long long)b * CDHW + (long long)cc * DHW + hw;
  float Ct = 0.f;
  for (int d = 0; d < D; ++d) {
    const long long idx = base + (long long)d * HW;
    float wx = tanhf(fmaf(g0[idx], sc[0], bi[0]));
    float ft = 1.f / (1.f + __expf(-fmaf(g1[idx], sc[1], bi[1])));
    float rt = 1.f / (1.f + __expf(-fmaf(g2[idx], sc[2], bi[2])));
    float xg = tanhf(fmaf(g3[idx], sc[3], bi[3]));
    Ct = (d == 0) ? (1.f - ft) : fmaf(ft, Ct, (1.f - ft) * wx);
    out[idx] = fmaf(rt, Ct, (1.f - rt) * xg);
  }
}

// ---------------------------------------------------------------------------
extern "C" void kernel_launch(void* const* d_in, const int* in_sizes, int n_in,
                              void* d_out, int out_size, void* d_ws, size_t ws_size,
                              hipStream_t stream) {
  const float* x      = (const float*)d_in[0];
  const float* w_pre  = (const float*)d_in[1];
  const float* bnpg   = (const float*)d_in[2];
  const float* bnpb   = (const float*)d_in[3];
  const float* bnpm   = (const float*)d_in[4];
  const float* bnpv   = (const float*)d_in[5];
  const float* wq     = (const float*)d_in[6];
  const float* wk     = (const float*)d_in[7];
  const float* wv     = (const float*)d_in[8];
  const float* gamma  = (const float*)d_in[9];
  const float* w_gate = (const float*)d_in[10];
  const float* bng    = (const float*)d_in[11];
  const float* bnb    = (const float*)d_in[12];
  const float* bnm    = (const float*)d_in[13];
  const float* bnv    = (const float*)d_in[14];

  float* ws  = (float*)d_ws;
  float* X1  = ws + OFF_X1;
  float* X2  = ws + OFF_X2;
  float* Q   = ws + OFF_Q;
  float* K   = ws + OFF_K;
  float* V   = ws + OFF_V;
  float* KT  = ws + OFF_KT;
  float* VT  = ws + OFF_VT;
  float* MST = ws + OFF_MST;
  float* G0  = ws + OFF_G0;
  float* G1  = ws + OFF_G1;
  float* G2  = ws + OFF_G2;
  float* WTb = ws + OFF_WT;
  float* out = (float*)d_out;

  // stage 1: conv_pre + BN + ReLU -> X1
  k_conv_pre<<<dim3(64, D, B), dim3(256), 0, stream>>>(x, w_pre, bnpg, bnpb, bnpm, bnpv, X1);

  // attention application 1: X1 -> X2
  k_qkv    <<<dim3(64, D, B), dim3(256), 0, stream>>>(X1, wq, wk, wv, Q, K, V, KT, VT);
  k_att_row<<<dim3(32, D, B), dim3(128), 0, stream>>>(X1, X2, Q, K, V, MST, gamma);
  k_att_col<<<dim3(32, D, B), dim3(128), 0, stream>>>(X2, Q, KT, VT, MST, gamma);

  // attention application 2: X2 -> X1
  k_qkv    <<<dim3(64, D, B), dim3(256), 0, stream>>>(X2, wq, wk, wv, Q, K, V, KT, VT);
  k_att_row<<<dim3(32, D, B), dim3(128), 0, stream>>>(X2, X1, Q, K, V, MST, gamma);
  k_att_col<<<dim3(32, D, B), dim3(128), 0, stream>>>(X1, Q, KT, VT, MST, gamma);

  // weight transpose for gates (MST region is free now)
  k_wt<<<dim3(108), dim3(256), 0, stream>>>(w_gate, WTb);

  // stage 3: conv_gate raw outputs (G0..G2 in ws, X gate into d_out)
  k_gates<<<dim3(32, D, B), dim3(256), 0, stream>>>(X1, WTb, G0, G1, G2, out);

  // stage 4: BN + activations + SRU scan
  k_scan<<<dim3(2048), dim3(256), 0, stream>>>(G0, G1, G2, out, bng, bnb, bnm, bnv, out);
}